// Round 6
// baseline (313.096 us; speedup 1.0000x reference)
//
#include <hip/hip_runtime.h>
#include <hip/hip_bf16.h>

#define HEADS 2
#define HIDD  128
#define DH    256      // HEADS*HIDD
#define NEG   0.2f
#define CAP   128      // per-wave LDS edge cache

typedef _Float16 half4 __attribute__((ext_vector_type(4)));
typedef _Float16 half2v __attribute__((ext_vector_type(2)));
typedef float    f32x4 __attribute__((ext_vector_type(4)));

// ---------------- prep: feat->fp16, W1/W2 -> transposed fp16, degree count ----------------

__global__ __launch_bounds__(256) void k_prep(const float* __restrict__ x,
                                              const float* __restrict__ rep,
                                              const float* __restrict__ W1,
                                              const float* __restrict__ W2,
                                              const int* __restrict__ dst,
                                              _Float16* __restrict__ feat16,
                                              _Float16* __restrict__ W1T,
                                              _Float16* __restrict__ W2T,
                                              int* __restrict__ deg,
                                              int N, int E) {
    int gid = blockIdx.x * 256 + threadIdx.x;
    int featQuads = N * 32;                 // N*128/4
    if (gid < featQuads) {
        int n = gid >> 5, d = (gid & 31) * 4;
        const float* s = (d < 64) ? (x + (size_t)n * 64 + d) : (rep + (size_t)n * 64 + (d - 64));
        float4 v = *reinterpret_cast<const float4*>(s);
        half4 o = { (_Float16)v.x, (_Float16)v.y, (_Float16)v.z, (_Float16)v.w };
        *reinterpret_cast<half4*>(feat16 + (size_t)n * 128 + d) = o;
        return;
    }
    gid -= featQuads;
    if (gid < 256 * 128) {                  // W1T[n][k] = W1[k][n], K=128
        int n = gid >> 7, k = gid & 127;
        W1T[n * 128 + k] = (_Float16)W1[(size_t)k * 256 + n];
        return;
    }
    gid -= 256 * 128;
    if (gid < 256 * 256) {                  // W2T[n][k] = W2[k][n], K=256
        int n = gid >> 8, k = gid & 255;
        W2T[n * 256 + k] = (_Float16)W2[(size_t)k * 256 + n];
        return;
    }
    gid -= 256 * 256;
    if (gid < E) atomicAdd(&deg[dst[gid]], 1);
}

// ---------------- scan (single block, int4 loads over zero-padded 32768 ints) ----------------

__global__ __launch_bounds__(1024) void k_scan(const int* __restrict__ deg,
                                               int* __restrict__ row_ptr,
                                               int* __restrict__ cursor, int n) {
    __shared__ int lds[1024];
    int tid = threadIdx.x;
    int base = tid * 32;
    int v[32];
#pragma unroll
    for (int k = 0; k < 8; ++k) {
        int4 q = *reinterpret_cast<const int4*>(deg + base + k * 4);
        v[k * 4 + 0] = q.x; v[k * 4 + 1] = q.y; v[k * 4 + 2] = q.z; v[k * 4 + 3] = q.w;
    }
    int local[32];
    int sum = 0;
#pragma unroll
    for (int k = 0; k < 32; ++k) { local[k] = sum; sum += v[k]; }
    lds[tid] = sum;
    __syncthreads();
    for (int off = 1; off < 1024; off <<= 1) {
        int t = (tid >= off) ? lds[tid - off] : 0;
        __syncthreads();
        lds[tid] += t;
        __syncthreads();
    }
    int thread_off = lds[tid] - sum;
#pragma unroll
    for (int k = 0; k < 32; ++k) {
        int i = base + k;
        if (i < n) {
            int rp = thread_off + local[k];
            row_ptr[i] = rp;
            cursor[i]  = rp;
        }
    }
    if (tid == 1023) row_ptr[n] = lds[1023];
}

__global__ void k_fill(const int* __restrict__ src, const int* __restrict__ dst,
                       int* __restrict__ cursor, int* __restrict__ csr_src, int E) {
    int e = blockIdx.x * blockDim.x + threadIdx.x;
    if (e < E) {
        int pos = atomicAdd(&cursor[dst[e]], 1);
        csr_src[pos] = src[e];
    }
}

// ---------------- MFMA GEMM + fused el/er ----------------
// C16[M,256] = A16[M,K] @ (BT16[256,K])^T ; BM=64, BN=128 (= one head), BK=64.

#define GBM 64
#define GBN 128
#define GBK 64

template<int K>
__global__ __launch_bounds__(256) void k_gemm16(const _Float16* __restrict__ A,
                                                const _Float16* __restrict__ BT,
                                                _Float16* __restrict__ C16,
                                                const float* __restrict__ alp,
                                                const float* __restrict__ arp,
                                                float* __restrict__ el,
                                                float* __restrict__ er, int M) {
    __shared__ _Float16 As[2][GBM * GBK];   // 16KB (reused as C-stage)
    __shared__ _Float16 Bs[2][GBN * GBK];   // 32KB

    int tid = threadIdx.x;
    int lane = tid & 63;
    int wave = tid >> 6;
    int row0 = blockIdx.x * GBM;
    int col0 = blockIdx.y * GBN;
    int wrow = (wave & 1) * 32;
    int wcol = (wave >> 1) * 64;

    uint4 ra[2], rb[4];
    const int am = tid >> 3;
    const int ak8 = (tid & 7) * 8;

    auto stage_load = [&](int s) {
        const _Float16* ap = A + (size_t)(row0 + am) * K + s * GBK + ak8;
        ra[0] = *reinterpret_cast<const uint4*>(ap);
        ra[1] = *reinterpret_cast<const uint4*>(ap + (size_t)32 * K);
        const _Float16* bp = BT + (size_t)(col0 + am) * K + s * GBK + ak8;
#pragma unroll
        for (int it = 0; it < 4; ++it)
            rb[it] = *reinterpret_cast<const uint4*>(bp + (size_t)(it * 32) * K);
    };
    auto stage_write = [&](int buf) {
        char* ab = (char*)As[buf];
        char* bb = (char*)Bs[buf];
#pragma unroll
        for (int it = 0; it < 2; ++it) {
            int m = am + it * 32;
            int byte = (m * 128 + ak8 * 2) ^ ((m & 7) << 4);
            *reinterpret_cast<uint4*>(ab + byte) = ra[it];
        }
#pragma unroll
        for (int it = 0; it < 4; ++it) {
            int n = am + it * 32;
            int byte = (n * 128 + ak8 * 2) ^ ((n & 7) << 4);
            *reinterpret_cast<uint4*>(bb + byte) = rb[it];
        }
    };

    f32x4 acc[2][4];
#pragma unroll
    for (int i = 0; i < 2; ++i)
#pragma unroll
        for (int j = 0; j < 4; ++j) acc[i][j] = (f32x4){0.f, 0.f, 0.f, 0.f};

    stage_load(0);
    stage_write(0);
    __syncthreads();

    const int S = K / GBK;
    for (int s = 0; s < S; ++s) {
        if (s + 1 < S) stage_load(s + 1);
        const char* ab = (const char*)As[s & 1];
        const char* bb = (const char*)Bs[s & 1];
#pragma unroll
        for (int kk = 0; kk < GBK / 16; ++kk) {
            half4 af[2], bf[4];
#pragma unroll
            for (int i = 0; i < 2; ++i) {
                int m = wrow + i * 16 + (lane & 15);
                int byte = (m * 128 + kk * 32 + (lane >> 4) * 8) ^ ((m & 7) << 4);
                af[i] = *reinterpret_cast<const half4*>(ab + byte);
            }
#pragma unroll
            for (int j = 0; j < 4; ++j) {
                int n = wcol + j * 16 + (lane & 15);
                int byte = (n * 128 + kk * 32 + (lane >> 4) * 8) ^ ((n & 7) << 4);
                bf[j] = *reinterpret_cast<const half4*>(bb + byte);
            }
#pragma unroll
            for (int i = 0; i < 2; ++i)
#pragma unroll
                for (int j = 0; j < 4; ++j)
                    acc[i][j] = __builtin_amdgcn_mfma_f32_16x16x16f16(af[i], bf[j], acc[i][j], 0, 0, 0);
        }
        if (s + 1 < S) stage_write((s + 1) & 1);
        __syncthreads();
    }

    // ---- epilogue: scatter accs into LDS C tile (swizzled), then coalesced IO ----
    char* Cs = (char*)As;                     // 64 rows x 256B = 16KB
    {
        int r4 = (lane >> 4) * 4, cl = lane & 15;
#pragma unroll
        for (int i = 0; i < 2; ++i)
#pragma unroll
            for (int j = 0; j < 4; ++j) {
                int col = wcol + j * 16 + cl;
#pragma unroll
                for (int r = 0; r < 4; ++r) {
                    int row = wrow + i * 16 + r4 + r;
                    int byte = (row * 256 + col * 2) ^ ((row & 7) << 4);
                    *reinterpret_cast<_Float16*>(Cs + byte) = (_Float16)acc[i][j][r];
                }
            }
    }
    __syncthreads();

#pragma unroll
    for (int it = 0; it < 4; ++it) {
        int lin = tid + it * 256;
        int row = lin >> 4, chunk = lin & 15;
        int gr = row0 + row;
        if (gr < M) {
            int byte = (row * 256 + chunk * 16) ^ ((row & 7) << 4);
            *reinterpret_cast<uint4*>(C16 + (size_t)gr * DH + col0 + chunk * 8) =
                *reinterpret_cast<const uint4*>(Cs + byte);
        }
    }

    // fused el/er: this block's 128 cols are one full head component
    {
        int r = lane >> 2, q = lane & 3;
        int row = wave * 16 + r;
        const float* alg = alp + col0;
        const float* arg = arp + col0;
        float els = 0.f, ers = 0.f;
#pragma unroll
        for (int kk = 0; kk < 4; ++kk) {
            int c0 = q * 32 + kk * 8;
            int byte = (row * 256 + c0 * 2) ^ ((row & 7) << 4);
            uint4 u = *reinterpret_cast<const uint4*>(Cs + byte);
            const _Float16* hv = (const _Float16*)&u;
#pragma unroll
            for (int t = 0; t < 8; ++t) {
                float hvv = (float)hv[t];
                els = fmaf(hvv, alg[c0 + t], els);
                ers = fmaf(hvv, arg[c0 + t], ers);
            }
        }
        els += __shfl_xor(els, 1); els += __shfl_xor(els, 2);
        ers += __shfl_xor(ers, 1); ers += __shfl_xor(ers, 2);
        int gr = row0 + row;
        if (q == 0 && gr < M) {
            el[gr * 2 + blockIdx.y] = els;
            er[gr * 2 + blockIdx.y] = ers;
        }
    }
}

// ---------------- aggregation: wave-per-(node,half) softmax + fp16 gather ----------------
// Feature dim split into 2 halves of 128; blockIdx%8 selects XCD; XCDs 0-3 take
// half 0, XCDs 4-7 take half 1 -> per-XCD gather working set halves (L2 locality).
// FINAL=false: write relu'd half-row to g (fp16).
// FINAL=true : project half-row onto fcW, write partial p[node][half] (float4).

template<bool FINAL>
__global__ __launch_bounds__(256) void k_agg(const _Float16* __restrict__ h,
                                             const float2* __restrict__ el2,
                                             const float2* __restrict__ er2,
                                             const int* __restrict__ row_ptr,
                                             const int* __restrict__ csr_src,
                                             const float* __restrict__ bias,
                                             _Float16* __restrict__ g,
                                             const float* __restrict__ fcW,
                                             float* __restrict__ p, int N) {
    __shared__ int    s_idx[4][CAP];
    __shared__ float2 s_a[4][CAP];

    int b = blockIdx.x;
    int xcd = b & 7;
    int half = xcd >> 2;
    int slot = (b >> 3) * 4 + (xcd & 3);
    int w = threadIdx.x >> 6, lane = threadIdx.x & 63;
    int node = slot * 4 + w;
    if (node >= N) return;    // no block-wide syncs anywhere
    int beg = row_ptr[node];
    int deg = row_ptr[node + 1] - beg;
    float2 er = er2[node];
    bool lo = lane < 32;

    // phase 1: scores + wave max (full softmax per half — el2 is L2-resident)
    float m0 = -__builtin_inff(), m1 = -__builtin_inff();
    for (int i = lane; i < deg; i += 64) {
        int s = csr_src[beg + i];
        float2 el = el2[s];
        float sc0 = el.x + er.x; sc0 = sc0 > 0.f ? sc0 : NEG * sc0;
        float sc1 = el.y + er.y; sc1 = sc1 > 0.f ? sc1 : NEG * sc1;
        if (i < CAP) { s_idx[w][i] = s; s_a[w][i] = make_float2(sc0, sc1); }
        m0 = fmaxf(m0, sc0);
        m1 = fmaxf(m1, sc1);
    }
#pragma unroll
    for (int off = 32; off; off >>= 1) {
        m0 = fmaxf(m0, __shfl_xor(m0, off));
        m1 = fmaxf(m1, __shfl_xor(m1, off));
    }

    // phase 2: exp + wave sum
    float sum0 = 0.f, sum1 = 0.f;
    for (int i = lane; i < deg; i += 64) {
        float2 sc;
        if (i < CAP) sc = s_a[w][i];
        else {
            int s = csr_src[beg + i];
            float2 el = el2[s];
            sc.x = el.x + er.x; sc.x = sc.x > 0.f ? sc.x : NEG * sc.x;
            sc.y = el.y + er.y; sc.y = sc.y > 0.f ? sc.y : NEG * sc.y;
        }
        float e0 = __expf(sc.x - m0);
        float e1 = __expf(sc.y - m1);
        if (i < CAP) s_a[w][i] = make_float2(e0, e1);
        sum0 += e0;
        sum1 += e1;
    }
#pragma unroll
    for (int off = 32; off; off >>= 1) {
        sum0 += __shfl_xor(sum0, off);
        sum1 += __shfl_xor(sum1, off);
    }
    // this wave's 128 features span one head-half? No: half splits features
    // [half*128, half*128+128) which lie entirely in head `half` ... wait:
    // head0 = feats 0-127, head1 = feats 128-255 -> half == head. Lane covers
    // 2 feats of that head; softmax uses that head's (m, S).
    float mh  = half ? m1 : m0;
    float Sh  = half ? sum1 : sum0;
    float inv = Sh > 0.f ? 1.f / Sh : 0.f;
    float erh = half ? er.y : er.x;

    // phase 3: fp16 gather (4B/lane/edge = 256B row-half), 8 edges in flight
    const _Float16* hp = h + half * 128 + lane * 2;
    float ax = 0.f, ay = 0.f;

#define FETCH(I, S_, A_)                                                    \
    do {                                                                     \
        int _i = (I);                                                        \
        if (_i < CAP) {                                                      \
            S_ = s_idx[w][_i];                                               \
            float2 _a2 = s_a[w][_i];                                         \
            A_ = half ? _a2.y : _a2.x;                                       \
        } else {                                                             \
            S_ = csr_src[beg + _i];                                          \
            float2 _el = el2[S_];                                            \
            float _sc = (half ? _el.y : _el.x) + erh;                        \
            _sc = _sc > 0.f ? _sc : NEG * _sc;                               \
            A_ = __expf(_sc - mh);                                           \
        }                                                                    \
    } while (0)

#define ACCUM(V, A_)                                                         \
    do {                                                                     \
        const _Float16* _hv = reinterpret_cast<const _Float16*>(&(V));       \
        ax = fmaf(A_, (float)_hv[0], ax);                                    \
        ay = fmaf(A_, (float)_hv[1], ay);                                    \
    } while (0)

    int i = 0;
    for (; i + 8 <= deg; i += 8) {
        int ss[8];
        float aa[8];
#pragma unroll
        for (int u = 0; u < 8; ++u) FETCH(i + u, ss[u], aa[u]);
        unsigned vv[8];
#pragma unroll
        for (int u = 0; u < 8; ++u)
            vv[u] = *reinterpret_cast<const unsigned*>(hp + (size_t)ss[u] * DH);
#pragma unroll
        for (int u = 0; u < 8; ++u) ACCUM(vv[u], aa[u]);
    }
    for (; i + 4 <= deg; i += 4) {
        int ss[4];
        float aa[4];
#pragma unroll
        for (int u = 0; u < 4; ++u) FETCH(i + u, ss[u], aa[u]);
        unsigned vv[4];
#pragma unroll
        for (int u = 0; u < 4; ++u)
            vv[u] = *reinterpret_cast<const unsigned*>(hp + (size_t)ss[u] * DH);
#pragma unroll
        for (int u = 0; u < 4; ++u) ACCUM(vv[u], aa[u]);
    }
    for (; i < deg; ++i) {
        int s;
        float a;
        FETCH(i, s, a);
        unsigned v = *reinterpret_cast<const unsigned*>(hp + (size_t)s * DH);
        ACCUM(v, a);
    }
#undef FETCH
#undef ACCUM

    int f = half * 128 + lane * 2;
    float2 bb = *reinterpret_cast<const float2*>(bias + f);
    float o0 = fmaxf(fmaf(ax, inv, bb.x), 0.f);
    float o1 = fmaxf(fmaf(ay, inv, bb.y), 0.f);

    if (!FINAL) {
        half2v o = { (_Float16)o0, (_Float16)o1 };
        *reinterpret_cast<half2v*>(g + (size_t)node * DH + f) = o;
    } else {
        // partial classifier projection for this half's 2 features
        float2 wt0 = *reinterpret_cast<const float2*>(&fcW[f * 2]);
        float2 wt1 = *reinterpret_cast<const float2*>(&fcW[(f + 1) * 2]);
        float2 wb0 = *reinterpret_cast<const float2*>(&fcW[(DH + f) * 2]);
        float2 wb1 = *reinterpret_cast<const float2*>(&fcW[(DH + f + 1) * 2]);
        float a0 = o0 * wt0.x + o1 * wt1.x;
        float a1 = o0 * wt0.y + o1 * wt1.y;
        float a2 = o0 * wb0.x + o1 * wb1.x;
        float a3 = o0 * wb0.y + o1 * wb1.y;
#pragma unroll
        for (int off = 32; off; off >>= 1) {
            a0 += __shfl_xor(a0, off);
            a1 += __shfl_xor(a1, off);
            a2 += __shfl_xor(a2, off);
            a3 += __shfl_xor(a3, off);
        }
        if (lane == 0)
            *reinterpret_cast<float4*>(&p[(size_t)node * 8 + half * 4]) =
                make_float4(a0, a1, a2, a3);
    }
}

// ---------------- edge output (sums half-partials) ----------------

__global__ void k_edgeout(const float* __restrict__ p,
                          const int* __restrict__ src,
                          const int* __restrict__ dst,
                          const float* __restrict__ fcb,
                          float* __restrict__ out, int E) {
    int e = blockIdx.x * blockDim.x + threadIdx.x;
    if (e >= E) return;
    int s = src[e], d = dst[e];
    float4 ps0 = *reinterpret_cast<const float4*>(&p[(size_t)s * 8]);
    float4 ps1 = *reinterpret_cast<const float4*>(&p[(size_t)s * 8 + 4]);
    float4 pd0 = *reinterpret_cast<const float4*>(&p[(size_t)d * 8]);
    float4 pd1 = *reinterpret_cast<const float4*>(&p[(size_t)d * 8 + 4]);
    float2 o;
    o.x = ps0.x + ps1.x + pd0.z + pd1.z + fcb[0];
    o.y = ps0.y + ps1.y + pd0.w + pd1.w + fcb[1];
    *reinterpret_cast<float2*>(&out[(size_t)e * 2]) = o;
}

// ---------------- launch ----------------

extern "C" void kernel_launch(void* const* d_in, const int* in_sizes, int n_in,
                              void* d_out, int out_size, void* d_ws, size_t ws_size,
                              hipStream_t stream) {
    const float* x   = (const float*)d_in[0];
    const float* rep = (const float*)d_in[1];
    const int*   src = (const int*)d_in[2];
    const int*   dst = (const int*)d_in[3];
    const float* W1  = (const float*)d_in[4];
    const float* al1 = (const float*)d_in[5];
    const float* ar1 = (const float*)d_in[6];
    const float* b1  = (const float*)d_in[7];
    const float* W2  = (const float*)d_in[8];
    const float* al2 = (const float*)d_in[9];
    const float* ar2 = (const float*)d_in[10];
    const float* b2  = (const float*)d_in[11];
    const float* fcW = (const float*)d_in[12];
    const float* fcb = (const float*)d_in[13];
    float* out = (float*)d_out;

    int N = in_sizes[0] / 64;   // 25000
    int E = in_sizes[2];        // 400000

    char* ws = (char*)d_ws;
    size_t off = 0;
    auto alloc = [&](size_t bytes) -> void* {
        void* ptr = ws + off;
        off = (off + bytes + 255) & ~(size_t)255;
        return ptr;
    };
    int*       deg     = (int*)alloc((size_t)32768 * 4);    // zero-padded for vector scan
    int*       row_ptr = (int*)alloc((size_t)(N + 1) * 4);
    int*       cursor  = (int*)alloc((size_t)N * 4);
    int*       csr_src = (int*)alloc((size_t)E * 4);
    _Float16*  feat16  = (_Float16*)alloc((size_t)N * 128 * 2);
    _Float16*  W1T     = (_Float16*)alloc((size_t)256 * 128 * 2);
    _Float16*  W2T     = (_Float16*)alloc((size_t)256 * 256 * 2);
    _Float16*  h16     = (_Float16*)alloc((size_t)N * DH * 2);
    _Float16*  g16     = (_Float16*)alloc((size_t)N * DH * 2);
    float*     el      = (float*)alloc((size_t)N * 2 * 4);
    float*     er      = (float*)alloc((size_t)N * 2 * 4);
    float*     p       = (float*)alloc((size_t)N * 8 * 4);
    (void)alloc(65536);   // tail slack: gemm stage reads up to 63 rows past M

    hipMemsetAsync(deg, 0, (size_t)32768 * 4, stream);

    int eb = (E + 255) / 256;
    int nb4 = (N + 3) / 4;                  // node-quads
    int aggG = ((nb4 + 3) / 4) * 8;         // XCD-partitioned half-feature grid
    int prep_blocks = (N * 32 + 256 * 128 + 256 * 256 + E + 255) / 256;

    k_prep<<<prep_blocks, 256, 0, stream>>>(x, rep, W1, W2, dst, feat16, W1T, W2T, deg, N, E);
    k_scan<<<1, 1024, 0, stream>>>(deg, row_ptr, cursor, N);
    k_fill<<<eb, 256, 0, stream>>>(src, dst, cursor, csr_src, E);

    dim3 ggrid((N + GBM - 1) / GBM, DH / GBN);
    // layer 1 (gemm writes h16 AND el/er)
    k_gemm16<128><<<ggrid, 256, 0, stream>>>(feat16, W1T, h16, al1, ar1, el, er, N);
    k_agg<false><<<aggG, 256, 0, stream>>>(h16, (const float2*)el, (const float2*)er,
                                           row_ptr, csr_src, b1, g16, nullptr, nullptr, N);
    // layer 2
    k_gemm16<256><<<ggrid, 256, 0, stream>>>(g16, W2T, h16, al2, ar2, el, er, N);
    k_agg<true><<<aggG, 256, 0, stream>>>(h16, (const float2*)el, (const float2*)er,
                                          row_ptr, csr_src, b2, nullptr, fcW, p, N);
    // edge output
    k_edgeout<<<eb, 256, 0, stream>>>(p, src, dst, fcb, out, E);
}